// Round 3
// baseline (2021.646 us; speedup 1.0000x reference)
//
#include <hip/hip_runtime.h>
#include <hip/hip_bf16.h>

using bf16 = __hip_bfloat16;

#define DEVFN static __device__ __forceinline__

constexpr int NN = 16384;
constexpr int EE = 65536;
constexpr int GG = 512;
constexpr float AVG_LOG_F = 1.0227308671603782f; // (sum d*log d, d=1..4, hist 1,2,3,4)/10

DEVFN float cvt(float v) { return v; }
DEVFN float cvt(bf16 v) { return __bfloat162float(v); }
DEVFN void stv(float* p, float v) { *p = v; }
DEVFN void stv(bf16* p, float v) { *p = __float2bfloat16(v); }

// ---------------------------------------------------------------------------
// Generic tiled SGEMM: C[M,Nc] = A[M,K] @ W[K,Nc] (+bias) (+relu)
// block 256, tile 64x64, BK=16, 4x4 micro-tile. fp32 accumulate.
// Requires M%64==0, K%16==0. Nc guarded.
// ---------------------------------------------------------------------------
template <typename TA, typename TO, bool BIAS, bool RELU>
__global__ __launch_bounds__(256) void sgemm(
    const TA* __restrict__ A, const float* __restrict__ W,
    const float* __restrict__ bias, TO* __restrict__ C,
    int M, int Nc, int K, int lda, int ldw, int ldc,
    long long bsA, long long bsW, long long bsC, int bsBias)
{
  const int z = blockIdx.z;
  A += (long long)z * bsA;
  W += (long long)z * bsW;
  C += (long long)z * bsC;
  if (BIAS) bias += (long long)z * bsBias;

  __shared__ float As[16][68];
  __shared__ float Ws[16][68];

  const int tid = threadIdx.x;
  const int bm = blockIdx.x * 64;
  const int bn = blockIdx.y * 64;
  const int tx = tid & 15, ty = tid >> 4;

  const int arow = tid >> 2;        // 0..63
  const int acol0 = (tid & 3) * 4;  // 0,4,8,12
  const int wrow = tid >> 4;        // 0..15
  const int wcol0 = (tid & 15) * 4; // 0..60

  float acc[4][4];
#pragma unroll
  for (int i = 0; i < 4; ++i)
#pragma unroll
    for (int j = 0; j < 4; ++j) acc[i][j] = 0.f;

  for (int k0 = 0; k0 < K; k0 += 16) {
    const long long abase = (long long)(bm + arow) * lda + k0 + acol0;
#pragma unroll
    for (int j = 0; j < 4; ++j) As[acol0 + j][arow] = cvt(A[abase + j]);
    const long long wbase = (long long)(k0 + wrow) * ldw + bn + wcol0;
#pragma unroll
    for (int j = 0; j < 4; ++j) {
      int n = bn + wcol0 + j;
      Ws[wrow][wcol0 + j] = (n < Nc) ? W[wbase + j] : 0.f;
    }
    __syncthreads();
#pragma unroll
    for (int kk = 0; kk < 16; ++kk) {
      float a[4], b[4];
#pragma unroll
      for (int i = 0; i < 4; ++i) a[i] = As[kk][ty * 4 + i];
#pragma unroll
      for (int j = 0; j < 4; ++j) b[j] = Ws[kk][tx * 4 + j];
#pragma unroll
      for (int i = 0; i < 4; ++i)
#pragma unroll
        for (int j = 0; j < 4; ++j) acc[i][j] += a[i] * b[j];
    }
    __syncthreads();
  }

#pragma unroll
  for (int i = 0; i < 4; ++i) {
    int m = bm + ty * 4 + i;
#pragma unroll
    for (int j = 0; j < 4; ++j) {
      int n = bn + tx * 4 + j;
      if (n >= Nc) continue;
      float v = acc[i][j];
      if (BIAS) v += bias[n];
      if (RELU) v = fmaxf(v, 0.f);
      stv(&C[(long long)m * ldc + n], v);
    }
  }
}

// ---------------------------------------------------------------------------
// Encoders
// ---------------------------------------------------------------------------
__global__ void node_enc(const float* __restrict__ x, const float* __restrict__ Wa,
                         const float* __restrict__ ba, float* __restrict__ h)
{
  int n = blockIdx.x, c = threadIdx.x; // 128
  float acc = ba[c];
#pragma unroll
  for (int k = 0; k < 11; ++k) acc += x[n * 11 + k] * Wa[k * 128 + c];
  h[(long long)n * 128 + c] = fmaxf(acc, 0.f);
}

__global__ void edge_enc(const float* __restrict__ eat, const float* __restrict__ We,
                         const float* __restrict__ be, float* __restrict__ ea)
{
  int e = blockIdx.x, c = threadIdx.x; // 128
  float acc = be[c];
#pragma unroll
  for (int k = 0; k < 4; ++k) acc += eat[e * 4 + k] * We[k * 128 + c];
  ea[(long long)e * 128 + c] = fmaxf(acc, 0.f);
}

// ---------------------------------------------------------------------------
// CSR build: count -> scan -> scatter
// ---------------------------------------------------------------------------
__global__ void count_deg(const int* __restrict__ dst, int* __restrict__ degi)
{
  int e = blockIdx.x * 256 + threadIdx.x;
  if (e < EE) atomicAdd(&degi[dst[e]], 1);
}

__global__ __launch_bounds__(1024) void scan_k(const int* __restrict__ degi, int* __restrict__ row_off)
{
  __shared__ int tsum[1024];
  int t = threadIdx.x;
  int local[16];
  int base = t * 16;
  int s = 0;
#pragma unroll
  for (int i = 0; i < 16; ++i) { local[i] = s; s += degi[base + i]; }
  tsum[t] = s;
  __syncthreads();
  for (int off = 1; off < 1024; off <<= 1) {
    int v = (t >= off) ? tsum[t - off] : 0;
    __syncthreads();
    tsum[t] += v;
    __syncthreads();
  }
  int prev = (t == 0) ? 0 : tsum[t - 1];
#pragma unroll
  for (int i = 0; i < 16; ++i) row_off[base + i] = prev + local[i];
  if (t == 1023) row_off[NN] = tsum[1023];
}

__global__ void scatter_k(const int* __restrict__ src, const int* __restrict__ dst,
                          const int* __restrict__ row_off, int* __restrict__ cursor,
                          int* __restrict__ eidx, int* __restrict__ esrc)
{
  int e = blockIdx.x * 256 + threadIdx.x;
  if (e >= EE) return;
  int d = dst[e];
  int pos = atomicAdd(&cursor[d], 1);
  int slot = row_off[d] + pos;
  eidx[slot] = e;
  esrc[slot] = src[e];
}

// ---------------------------------------------------------------------------
// Weight packing / algebraic folds
// ---------------------------------------------------------------------------
// WpreABp[l][t][k][j], j in 0..255: j<128 -> A (dst rows k), j>=128 -> B (src rows 128+k)
__global__ void pack_preAB(const float* __restrict__ Wpre, float* __restrict__ out)
{
  int k = blockIdx.x & 127;
  int lt = blockIdx.x >> 7; // l*4+t
  int j = threadIdx.x;      // 256
  int row = (j < 128) ? k : (128 + (k));
  int f = j & 127;
  out[((long long)(lt * 128 + k)) * 256 + j] =
      Wpre[((long long)(lt * 384 + row)) * 128 + f];
}

// Wfold[l][k][t*128+f] = sum_j We_conv[l][k][j] * Wpre[l][t][256+j][f]
__global__ __launch_bounds__(512) void fold_w(const float* __restrict__ We_conv,
                                              const float* __restrict__ Wpre,
                                              float* __restrict__ Wfold)
{
  int k = blockIdx.x & 127, l = blockIdx.x >> 7;
  int t = threadIdx.x >> 7, f = threadIdx.x & 127;
  const float* wc = We_conv + (long long)(l * 128 + k) * 128;
  const float* wp = Wpre + ((long long)((l * 4 + t) * 384 + 256)) * 128 + f;
  float acc = 0.f;
  for (int j = 0; j < 128; ++j) acc += wc[j] * wp[(long long)j * 128];
  Wfold[((long long)(l * 128 + k)) * 512 + threadIdx.x] = acc;
}

// bfold[l][t*128+f] = sum_j be_conv[l][j]*Wpre[l][t][256+j][f] + bpre[l][t][f]
__global__ __launch_bounds__(512) void fold_b(const float* __restrict__ be_conv,
                                              const float* __restrict__ Wpre,
                                              const float* __restrict__ bpre,
                                              float* __restrict__ bfold)
{
  int l = blockIdx.x;
  int t = threadIdx.x >> 7, f = threadIdx.x & 127;
  const float* bc = be_conv + l * 128;
  const float* wp = Wpre + ((long long)((l * 4 + t) * 384 + 256)) * 128 + f;
  float acc = bpre[(l * 4 + t) * 128 + f];
  for (int j = 0; j < 128; ++j) acc += bc[j] * wp[(long long)j * 128];
  bfold[l * 512 + threadIdx.x] = acc;
}

// Wpost3[l][t][r=stat*128+f][c=part*32+o] = Wpost[l][t][128 + part*512 + r][o]
__global__ void pack_post3(const float* __restrict__ Wpost, float* __restrict__ out)
{
  int row = blockIdx.x & 511;
  int t = (blockIdx.x >> 9) & 3;
  int l = blockIdx.x >> 11;
  int c = threadIdx.x;
  int part = c >> 5, o = c & 31;
  out[((long long)((l * 4 + t) * 512 + row)) * 96 + c] =
      Wpost[((long long)((l * 4 + t) * 1664 + 128 + part * 512 + row)) * 32 + o];
}

// Wx[l][k][t*32+o] = Wpost[l][t][k][o]  (x-part, rows 0:128)
__global__ void pack_wx(const float* __restrict__ Wpost, float* __restrict__ out)
{
  int k = blockIdx.x & 127, l = blockIdx.x >> 7;
  int c = threadIdx.x;
  int t = c >> 5, o = c & 31;
  out[((long long)(l * 128 + k)) * 128 + c] =
      Wpost[((long long)((l * 4 + t) * 1664 + k)) * 32 + o];
}

// ---------------------------------------------------------------------------
// Per-tower aggregation: m = ABt[n][c] + ABt[src][128+c] + Ct[e][c]  (all fp32)
// aggt output fp32 [N][mean|min|max|std (128 each)]
// ---------------------------------------------------------------------------
__global__ __launch_bounds__(128) void aggregate_t(
    const float* __restrict__ ABt, // [N][256]: 0:128 A(dst-part), 128:256 B(src-part)
    const float* __restrict__ Ct,  // [E][128]
    const int* __restrict__ row_off, const int* __restrict__ eidx,
    const int* __restrict__ esrc,
    float* __restrict__ aggt,      // [N][512]
    float* __restrict__ s_arr, float* __restrict__ invs_arr)
{
  int n = blockIdx.x;
  int c = threadIdx.x; // 128
  int beg = row_off[n], end = row_off[n + 1];
  int cnt = end - beg;
  float degc = fmaxf((float)cnt, 1.0f);

  float sum = 0.f, sq = 0.f;
  float mn = INFINITY, mx = -INFINITY;
  float aval = ABt[(long long)n * 256 + c];

  for (int slot = beg; slot < end; ++slot) {
    int e = eidx[slot];
    int sidx = esrc[slot];
    float m = aval + ABt[(long long)sidx * 256 + 128 + c] +
              Ct[(long long)e * 128 + c];
    sum += m;
    sq += m * m;
    mn = fminf(mn, m);
    mx = fmaxf(mx, m);
  }

  if (c == 0) {
    float s = logf(degc + 1.0f) / AVG_LOG_F;
    s_arr[n] = s;
    invs_arr[n] = 1.0f / s;
  }

  float inv = 1.0f / degc;
  float mean = sum * inv;
  float mean2 = sq * inv;
  float var = mean2 - mean * mean;
  float stdv = sqrtf(fmaxf(var, 0.f) + 1e-5f);
  float mnv = (cnt > 0) ? mn : 0.f;
  float mxv = (cnt > 0) ? mx : 0.f;
  long long base = (long long)n * 512 + c;
  aggt[base] = mean;
  aggt[base + 128] = mnv;
  aggt[base + 256] = mxv;
  aggt[base + 384] = stdv;
}

// post[n][t*32+o] = Px + P_id + s*P_amp + (1/s)*P_att + bpost
__global__ void combine_post(const float* __restrict__ P,  // [N][384]
                             const float* __restrict__ Px, // [N][128]
                             const float* __restrict__ s_arr,
                             const float* __restrict__ invs_arr,
                             const float* __restrict__ bpost_l, // [128]
                             float* __restrict__ post)          // [N][128]
{
  int n = blockIdx.x, c = threadIdx.x; // 128
  int t = c >> 5, o = c & 31;
  const float* p = P + (long long)n * 384 + t * 96 + o;
  float v = Px[(long long)n * 128 + c] + p[0] + s_arr[n] * p[32] +
            invs_arr[n] * p[64] + bpost_l[c];
  post[(long long)n * 128 + c] = v;
}

// ---------------------------------------------------------------------------
// BatchNorm over N rows, 128 cols (training-mode batch stats, biased var)
// ---------------------------------------------------------------------------
__global__ __launch_bounds__(256) void bn_partial(const float* __restrict__ y,
                                                  float* __restrict__ colsum,
                                                  float* __restrict__ colsq)
{
  int c = threadIdx.x & 127;
  int rh = threadIdx.x >> 7;
  int r0 = blockIdx.x * 128;
  float s = 0.f, q = 0.f;
  for (int r = r0 + rh; r < r0 + 128; r += 2) {
    float v = y[(long long)r * 128 + c];
    s += v;
    q += v * v;
  }
  __shared__ float ps[256], pq[256];
  ps[threadIdx.x] = s;
  pq[threadIdx.x] = q;
  __syncthreads();
  if (threadIdx.x < 128) {
    atomicAdd(&colsum[c], ps[c] + ps[c + 128]);
    atomicAdd(&colsq[c], pq[c] + pq[c + 128]);
  }
}

__global__ void bn_apply(const float* __restrict__ y, const float* __restrict__ colsum,
                         const float* __restrict__ colsq, const float* __restrict__ g,
                         const float* __restrict__ b, float* __restrict__ hout)
{
  int n = blockIdx.x, c = threadIdx.x;
  float mean = colsum[c] * (1.f / 16384.f);
  float var = colsq[c] * (1.f / 16384.f) - mean * mean;
  float v = (y[(long long)n * 128 + c] - mean) * rsqrtf(var + 1e-5f) * g[c] + b[c];
  hout[(long long)n * 128 + c] = fmaxf(v, 0.f);
}

// ---------------------------------------------------------------------------
// Global mean pool + head
// ---------------------------------------------------------------------------
__global__ void pool_add(const float* __restrict__ h, const int* __restrict__ batch,
                         float* __restrict__ pooled, float* __restrict__ cntf)
{
  int n = blockIdx.x, c = threadIdx.x;
  int b = batch[n];
  atomicAdd(&pooled[(long long)b * 128 + c], h[(long long)n * 128 + c]);
  if (c == 0) atomicAdd(&cntf[b], 1.f);
}

__global__ void pool_div(float* __restrict__ pooled, const float* __restrict__ cntf)
{
  int g = blockIdx.x, c = threadIdx.x;
  pooled[(long long)g * 128 + c] /= fmaxf(cntf[g], 1.f);
}

__global__ __launch_bounds__(256) void zstats(const float* __restrict__ z,
                                              float* __restrict__ zm, float* __restrict__ zv)
{
  int j = blockIdx.x; // 64 cols
  float s = 0.f, q = 0.f;
  for (int g = threadIdx.x; g < GG; g += 256) {
    float v = z[g * 64 + j];
    s += v;
    q += v * v;
  }
  __shared__ float ps[256], pq[256];
  ps[threadIdx.x] = s;
  pq[threadIdx.x] = q;
  __syncthreads();
  for (int st = 128; st > 0; st >>= 1) {
    if (threadIdx.x < st) {
      ps[threadIdx.x] += ps[threadIdx.x + st];
      pq[threadIdx.x] += pq[threadIdx.x + st];
    }
    __syncthreads();
  }
  if (threadIdx.x == 0) {
    float m = ps[0] / (float)GG;
    zm[j] = m;
    zv[j] = pq[0] / (float)GG - m * m;
  }
}

__global__ void final_out(const float* __restrict__ z, const float* __restrict__ zm,
                          const float* __restrict__ zv, const float* __restrict__ hg,
                          const float* __restrict__ hb, const float* __restrict__ W2,
                          const float* __restrict__ b2, float* __restrict__ out)
{
  int g = blockIdx.x;
  int j = threadIdx.x; // 64 = one wave
  float v = (z[g * 64 + j] - zm[j]) * rsqrtf(zv[j] + 1e-5f) * hg[j] + hb[j];
  float t = v * W2[j];
#pragma unroll
  for (int off = 32; off > 0; off >>= 1) t += __shfl_down(t, off);
  if (j == 0) out[g] = t + b2[0];
}

// ---------------------------------------------------------------------------
extern "C" void kernel_launch(void* const* d_in, const int* in_sizes, int n_in,
                              void* d_out, int out_size, void* d_ws, size_t ws_size,
                              hipStream_t stream)
{
  (void)in_sizes; (void)n_in; (void)out_size;
  const float* x = (const float*)d_in[0];
  const float* eat = (const float*)d_in[1];
  const int* ei = (const int*)d_in[2];
  const int* batch = (const int*)d_in[3];
  const float* Wa = (const float*)d_in[4];
  const float* ba = (const float*)d_in[5];
  const float* We = (const float*)d_in[6];
  const float* be = (const float*)d_in[7];
  const float* We_conv = (const float*)d_in[8];
  const float* be_conv = (const float*)d_in[9];
  const float* Wpre = (const float*)d_in[10];
  const float* bpre = (const float*)d_in[11];
  const float* Wpost = (const float*)d_in[12];
  const float* bpost = (const float*)d_in[13];
  const float* Wlin = (const float*)d_in[14];
  const float* blin = (const float*)d_in[15];
  const float* bng = (const float*)d_in[16];
  const float* bnb = (const float*)d_in[17];
  const float* W1 = (const float*)d_in[18];
  const float* b1 = (const float*)d_in[19];
  const float* hg = (const float*)d_in[20];
  const float* hb = (const float*)d_in[21];
  const float* W2 = (const float*)d_in[22];
  const float* b2 = (const float*)d_in[23];
  float* out = (float*)d_out;

  const int* srcI = ei;
  const int* dstI = ei + EE;

  char* ws = (char*)d_ws;
  size_t off = 0;
  auto alloc = [&](size_t bytes) -> char* {
    char* p = ws + off;
    off += (bytes + 255) & ~(size_t)255;
    return p;
  };

  // Workspace (all fp32; total ~166 MB, under the proven ~207 MB ceiling)
  float* h0 = (float*)alloc((size_t)NN * 128 * 4);       //  8.4 MB
  float* h1 = (float*)alloc((size_t)NN * 128 * 4);       //  8.4 MB
  float* ea = (float*)alloc((size_t)EE * 128 * 4);       // 33.6 MB
  float* ABt = (float*)alloc((size_t)NN * 256 * 4);      // 16.8 MB (per-tower)
  char* Cregion = alloc((size_t)EE * 128 * 4);           // 33.6 MB (per-tower Ct; later Px|post)
  float* Ct = (float*)Cregion;
  float* Px = (float*)Cregion;                           // [N][128] = 8.4 MB
  float* post = (float*)(Cregion + (size_t)NN * 128 * 4); // [N][128] = 8.4 MB
  float* aggt = (float*)alloc((size_t)NN * 512 * 4);     // 33.6 MB (per-tower)
  float* P = (float*)alloc((size_t)NN * 384 * 4);        // 25.2 MB
  float* s_arr = (float*)alloc((size_t)NN * 4);
  float* invs = (float*)alloc((size_t)NN * 4);
  int* degi = (int*)alloc((size_t)NN * 4);
  int* cursor = (int*)alloc((size_t)NN * 4);
  int* row_off = (int*)alloc((size_t)(NN + 1) * 4);
  int* eidx = (int*)alloc((size_t)EE * 4);
  int* esrc = (int*)alloc((size_t)EE * 4);
  float* WpreABp = (float*)alloc((size_t)3 * 4 * 128 * 256 * 4); // 1.6 MB
  float* Wfold = (float*)alloc((size_t)3 * 128 * 512 * 4);
  float* bfold = (float*)alloc((size_t)3 * 512 * 4);
  float* Wpost3 = (float*)alloc((size_t)3 * 4 * 512 * 96 * 4);
  float* Wx = (float*)alloc((size_t)3 * 128 * 128 * 4);
  float* colstats = (float*)alloc(256 * 4);
  float* pooled = (float*)alloc((size_t)GG * 128 * 4);
  float* cntf = (float*)alloc((size_t)GG * 4);
  float* z = (float*)alloc((size_t)GG * 64 * 4);
  float* zm = (float*)alloc(64 * 4);
  float* zv = (float*)alloc(64 * 4);

  if (off > ws_size) return; // workspace too small — bail rather than corrupt

  // ---- graph structure ----
  hipMemsetAsync(degi, 0, (size_t)NN * 4, stream);
  hipMemsetAsync(cursor, 0, (size_t)NN * 4, stream);
  count_deg<<<EE / 256, 256, 0, stream>>>(dstI, degi);
  scan_k<<<1, 1024, 0, stream>>>(degi, row_off);
  scatter_k<<<EE / 256, 256, 0, stream>>>(srcI, dstI, row_off, cursor, eidx, esrc);

  // ---- encoders + weight packing ----
  node_enc<<<NN, 128, 0, stream>>>(x, Wa, ba, h0);
  edge_enc<<<EE, 128, 0, stream>>>(eat, We, be, ea);
  pack_preAB<<<1536, 256, 0, stream>>>(Wpre, WpreABp);
  fold_w<<<384, 512, 0, stream>>>(We_conv, Wpre, Wfold);
  fold_b<<<3, 512, 0, stream>>>(be_conv, Wpre, bpre, bfold);
  pack_post3<<<6144, 96, 0, stream>>>(Wpost, Wpost3);
  pack_wx<<<384, 128, 0, stream>>>(Wpost, Wx);

  float* hc = h0;
  float* hn = h1;
  for (int l = 0; l < 3; ++l) {
    for (int t = 0; t < 4; ++t) {
      // ABt: [N,128] @ [128,256] -> fp32 [N,256] (A|B for tower t)
      sgemm<float, float, false, false><<<dim3(NN / 64, 4, 1), 256, 0, stream>>>(
          hc, WpreABp + ((size_t)(l * 4 + t) * 128) * 256, nullptr, ABt,
          NN, 256, 128, 128, 256, 256, 0, 0, 0, 0);
      // Ct: [E,128] @ [128,128] + bfold_t -> fp32 [E,128]
      sgemm<float, float, true, false><<<dim3(EE / 64, 2, 1), 256, 0, stream>>>(
          ea, Wfold + (size_t)l * 128 * 512 + t * 128, bfold + l * 512 + t * 128, Ct,
          EE, 128, 128, 128, 512, 128, 0, 0, 0, 0);
      aggregate_t<<<NN, 128, 0, stream>>>(ABt, Ct, row_off, eidx, esrc, aggt, s_arr, invs);
      // P tower slice: [N,512] @ [512,96] -> fp32 P[:, t*96 : t*96+96]
      sgemm<float, float, false, false><<<dim3(NN / 64, 2, 1), 256, 0, stream>>>(
          aggt, Wpost3 + (size_t)(l * 4 + t) * 512 * 96, nullptr, P + t * 96,
          NN, 96, 512, 512, 96, 384, 0, 0, 0, 0);
    }
    // Px: [N,128] @ [128,128] -> fp32 [N,128]  (aliases dead Ct region)
    sgemm<float, float, false, false><<<dim3(NN / 64, 2, 1), 256, 0, stream>>>(
        hc, Wx + (size_t)l * 128 * 128, nullptr, Px,
        NN, 128, 128, 128, 128, 128, 0, 0, 0, 0);
    combine_post<<<NN, 128, 0, stream>>>(P, Px, s_arr, invs, bpost + l * 128, post);
    // lin: [N,128] @ [128,128] + blin
    sgemm<float, float, true, false><<<dim3(NN / 64, 2, 1), 256, 0, stream>>>(
        post, Wlin + (size_t)l * 128 * 128, blin + l * 128, hn,
        NN, 128, 128, 128, 128, 128, 0, 0, 0, 0);
    hipMemsetAsync(colstats, 0, 256 * 4, stream);
    bn_partial<<<128, 256, 0, stream>>>(hn, colstats, colstats + 128);
    bn_apply<<<NN, 128, 0, stream>>>(hn, colstats, colstats + 128,
                                     bng + l * 128, bnb + l * 128, hn);
    float* tmp = hc; hc = hn; hn = tmp;
  }

  // ---- pooling + head ----
  hipMemsetAsync(pooled, 0, (size_t)GG * 128 * 4, stream);
  hipMemsetAsync(cntf, 0, (size_t)GG * 4, stream);
  pool_add<<<NN, 128, 0, stream>>>(hc, batch, pooled, cntf);
  pool_div<<<GG, 128, 0, stream>>>(pooled, cntf);
  sgemm<float, float, true, true><<<dim3(GG / 64, 1, 1), 256, 0, stream>>>(
      pooled, W1, b1, z, GG, 64, 128, 128, 64, 64, 0, 0, 0, 0);
  zstats<<<64, 256, 0, stream>>>(z, zm, zv);
  final_out<<<GG, 64, 0, stream>>>(z, zm, zv, hg, hb, W2, b2, out);
}

// Round 4
// 1177.875 us; speedup vs baseline: 1.7163x; 1.7163x over previous
//
#include <hip/hip_runtime.h>
#include <hip/hip_bf16.h>

#define DEVFN static __device__ __forceinline__

constexpr int NN = 16384;
constexpr int EE = 65536;
constexpr int GG = 512;
constexpr float AVG_LOG_F = 1.0227308671603782f; // (sum d*log d, d=1..4, hist 1,2,3,4)/10

typedef __attribute__((ext_vector_type(8))) short bfrag; // 8 bf16 = 4 VGPR
typedef __attribute__((ext_vector_type(4))) float f4;    // MFMA C/D

// fp32 -> bf16 (RNE) bit helpers
DEVFN unsigned short f2bf(float f) {
  unsigned int u = __float_as_uint(f);
  unsigned int r = (u + 0x7fffu + ((u >> 16) & 1u)) >> 16;
  return (unsigned short)r;
}
DEVFN float bf2f(unsigned short s) { return __uint_as_float(((unsigned int)s) << 16); }

// ---------------------------------------------------------------------------
// Split-bf16 MFMA GEMM: C[M,Nc] = A[M,K](fp32) @ W[K,Nc](fp32, pre-split)
// W supplied as WThi/WTlo: bf16 bits, transposed [Npad][K] row-major.
// acc = Ahi*Whi + Alo*Whi + Ahi*Wlo  (fp32 MFMA accumulate) ~= fp32 GEMM.
// Block: 256 thr = 4 waves; tile M=128 (wave: 32 rows), N=64, BK=32.
// Requires M%128==0, K%32==0; cols guarded vs Nc (WT zero-padded to Npad=64*grid.y).
// ---------------------------------------------------------------------------
template <bool BIAS, bool RELU>
__global__ __launch_bounds__(256) void mgemm(
    const float* __restrict__ A, const unsigned short* __restrict__ WThi,
    const unsigned short* __restrict__ WTlo, const float* __restrict__ bias,
    float* __restrict__ C, int Nc, int K, int lda, int ldc)
{
  __shared__ __align__(16) unsigned short Ah[128][40];
  __shared__ __align__(16) unsigned short Al[128][40];
  __shared__ __align__(16) unsigned short Bh[64][40];
  __shared__ __align__(16) unsigned short Bl[64][40];

  const int tid = threadIdx.x;
  const long long bm = (long long)blockIdx.x * 128;
  const int bn = blockIdx.y * 64;
  const int w = tid >> 6;
  const int lane = tid & 63;
  const int quad = lane >> 4;
  const int c16 = lane & 15;

  const int arow = tid >> 1;        // 0..127
  const int acb = (tid & 1) * 16;   // 0 or 16
  const int brow = tid >> 2;        // 0..63
  const int bk8 = (tid & 3) * 8;    // 0,8,16,24

  f4 acc[2][4];
#pragma unroll
  for (int mt = 0; mt < 2; ++mt)
#pragma unroll
    for (int nt = 0; nt < 4; ++nt) acc[mt][nt] = (f4){0.f, 0.f, 0.f, 0.f};

  const float* aptr = A + (bm + arow) * lda + acb;
  const unsigned short* whp = WThi + (long long)(bn + brow) * K + bk8;
  const unsigned short* wlp = WTlo + (long long)(bn + brow) * K + bk8;

  for (int k0 = 0; k0 < K; k0 += 32) {
    // ---- stage A (fp32 -> split hi/lo bf16) ----
    const float* ap = aptr + k0;
    float4 v0 = *(const float4*)(ap);
    float4 v1 = *(const float4*)(ap + 4);
    float4 v2 = *(const float4*)(ap + 8);
    float4 v3 = *(const float4*)(ap + 12);
    float va[16] = {v0.x, v0.y, v0.z, v0.w, v1.x, v1.y, v1.z, v1.w,
                    v2.x, v2.y, v2.z, v2.w, v3.x, v3.y, v3.z, v3.w};
#pragma unroll
    for (int i = 0; i < 16; ++i) {
      unsigned short h = f2bf(va[i]);
      Ah[arow][acb + i] = h;
      Al[arow][acb + i] = f2bf(va[i] - bf2f(h));
    }
    // ---- stage B (pre-split bf16, direct copy) ----
    *(uint4*)&Bh[brow][bk8] = *(const uint4*)(whp + k0);
    *(uint4*)&Bl[brow][bk8] = *(const uint4*)(wlp + k0);
    __syncthreads();

    bfrag ah[2], al[2];
#pragma unroll
    for (int mt = 0; mt < 2; ++mt) {
      int r = w * 32 + mt * 16 + c16;
      ah[mt] = *(const bfrag*)&Ah[r][quad * 8];
      al[mt] = *(const bfrag*)&Al[r][quad * 8];
    }
#pragma unroll
    for (int nt = 0; nt < 4; ++nt) {
      int r = nt * 16 + c16;
      bfrag bh = *(const bfrag*)&Bh[r][quad * 8];
      bfrag bl = *(const bfrag*)&Bl[r][quad * 8];
#pragma unroll
      for (int mt = 0; mt < 2; ++mt) {
        acc[mt][nt] = __builtin_amdgcn_mfma_f32_16x16x32_bf16(ah[mt], bh, acc[mt][nt], 0, 0, 0);
        acc[mt][nt] = __builtin_amdgcn_mfma_f32_16x16x32_bf16(al[mt], bh, acc[mt][nt], 0, 0, 0);
        acc[mt][nt] = __builtin_amdgcn_mfma_f32_16x16x32_bf16(ah[mt], bl, acc[mt][nt], 0, 0, 0);
      }
    }
    __syncthreads();
  }

  // ---- epilogue: C/D layout col=lane&15, row=quad*4+reg ----
#pragma unroll
  for (int nt = 0; nt < 4; ++nt) {
    int col = bn + nt * 16 + c16;
    if (col >= Nc) continue;
    float bv = BIAS ? bias[col] : 0.f;
#pragma unroll
    for (int mt = 0; mt < 2; ++mt) {
#pragma unroll
      for (int r = 0; r < 4; ++r) {
        long long row = bm + w * 32 + mt * 16 + quad * 4 + r;
        float v = acc[mt][nt][r] + bv;
        if (RELU) v = fmaxf(v, 0.f);
        C[row * ldc + col] = v;
      }
    }
  }
}

// ---------------------------------------------------------------------------
// Encoders
// ---------------------------------------------------------------------------
__global__ void node_enc(const float* __restrict__ x, const float* __restrict__ Wa,
                         const float* __restrict__ ba, float* __restrict__ h)
{
  int n = blockIdx.x, c = threadIdx.x; // 128
  float acc = ba[c];
#pragma unroll
  for (int k = 0; k < 11; ++k) acc += x[n * 11 + k] * Wa[k * 128 + c];
  h[(long long)n * 128 + c] = fmaxf(acc, 0.f);
}

__global__ void edge_enc(const float* __restrict__ eat, const float* __restrict__ We,
                         const float* __restrict__ be, float* __restrict__ ea)
{
  int e = blockIdx.x, c = threadIdx.x; // 128
  float acc = be[c];
#pragma unroll
  for (int k = 0; k < 4; ++k) acc += eat[e * 4 + k] * We[k * 128 + c];
  ea[(long long)e * 128 + c] = fmaxf(acc, 0.f);
}

// ---------------------------------------------------------------------------
// CSR build: count -> scan -> scatter
// ---------------------------------------------------------------------------
__global__ void count_deg(const int* __restrict__ dst, int* __restrict__ degi)
{
  int e = blockIdx.x * 256 + threadIdx.x;
  if (e < EE) atomicAdd(&degi[dst[e]], 1);
}

__global__ __launch_bounds__(1024) void scan_k(const int* __restrict__ degi, int* __restrict__ row_off)
{
  __shared__ int tsum[1024];
  int t = threadIdx.x;
  int local[16];
  int base = t * 16;
  int s = 0;
#pragma unroll
  for (int i = 0; i < 16; ++i) { local[i] = s; s += degi[base + i]; }
  tsum[t] = s;
  __syncthreads();
  for (int off = 1; off < 1024; off <<= 1) {
    int v = (t >= off) ? tsum[t - off] : 0;
    __syncthreads();
    tsum[t] += v;
    __syncthreads();
  }
  int prev = (t == 0) ? 0 : tsum[t - 1];
#pragma unroll
  for (int i = 0; i < 16; ++i) row_off[base + i] = prev + local[i];
  if (t == 1023) row_off[NN] = tsum[1023];
}

__global__ void scatter_k(const int* __restrict__ src, const int* __restrict__ dst,
                          const int* __restrict__ row_off, int* __restrict__ cursor,
                          int* __restrict__ eidx, int* __restrict__ esrc)
{
  int e = blockIdx.x * 256 + threadIdx.x;
  if (e >= EE) return;
  int d = dst[e];
  int pos = atomicAdd(&cursor[d], 1);
  int slot = row_off[d] + pos;
  eidx[slot] = e;
  esrc[slot] = src[e];
}

// ---------------------------------------------------------------------------
// Weight folds (fp32) + transpose-split packers (fp32 -> bf16 hi/lo, [N][K])
// ---------------------------------------------------------------------------
// Wfold[l][k][t*128+f] = sum_j We_conv[l][k][j] * Wpre[l][t][256+j][f]
__global__ __launch_bounds__(512) void fold_w(const float* __restrict__ We_conv,
                                              const float* __restrict__ Wpre,
                                              float* __restrict__ Wfold)
{
  int k = blockIdx.x & 127, l = blockIdx.x >> 7;
  int t = threadIdx.x >> 7, f = threadIdx.x & 127;
  const float* wc = We_conv + (long long)(l * 128 + k) * 128;
  const float* wp = Wpre + ((long long)((l * 4 + t) * 384 + 256)) * 128 + f;
  float acc = 0.f;
  for (int j = 0; j < 128; ++j) acc += wc[j] * wp[(long long)j * 128];
  Wfold[((long long)(l * 128 + k)) * 512 + threadIdx.x] = acc;
}

// bfold[l][t*128+f] = sum_j be_conv[l][j]*Wpre[l][t][256+j][f] + bpre[l][t][f]
__global__ __launch_bounds__(512) void fold_b(const float* __restrict__ be_conv,
                                              const float* __restrict__ Wpre,
                                              const float* __restrict__ bpre,
                                              float* __restrict__ bfold)
{
  int l = blockIdx.x;
  int t = threadIdx.x >> 7, f = threadIdx.x & 127;
  const float* bc = be_conv + l * 128;
  const float* wp = Wpre + ((long long)((l * 4 + t) * 384 + 256)) * 128 + f;
  float acc = bpre[(l * 4 + t) * 128 + f];
  for (int j = 0; j < 128; ++j) acc += bc[j] * wp[(long long)j * 128];
  bfold[l * 512 + threadIdx.x] = acc;
}

DEVFN void wsplit(float v, unsigned short* hi, unsigned short* lo, long long o)
{
  unsigned short h = f2bf(v);
  hi[o] = h;
  lo[o] = f2bf(v - bf2f(h));
}

// preABT[lt][n(256)][k(128)]: n<128 -> A part (Wpre row k, f=n); n>=128 -> B part (row 128+k)
__global__ void tsplit_preAB(const float* __restrict__ Wpre,
                             unsigned short* __restrict__ hi, unsigned short* __restrict__ lo)
{
  int b = blockIdx.x; // 12*256
  int lt = b >> 8, n = b & 255, k = threadIdx.x; // 128
  int row = (n < 128) ? k : (128 + k);
  int f = n & 127;
  float v = Wpre[((long long)(lt * 384 + row)) * 128 + f];
  wsplit(v, hi, lo, ((long long)(lt * 256 + n)) * 128 + k);
}

// WfoldT[lt][n(128)][k(128)] from Wfold[l][k][t*128+n]
__global__ void tsplit_fold(const float* __restrict__ Wfold,
                            unsigned short* __restrict__ hi, unsigned short* __restrict__ lo)
{
  int b = blockIdx.x; // 12*128
  int lt = b >> 7, n = b & 127, k = threadIdx.x; // 128
  int l = lt >> 2, t = lt & 3;
  float v = Wfold[((long long)(l * 128 + k)) * 512 + t * 128 + n];
  wsplit(v, hi, lo, ((long long)(lt * 128 + n)) * 128 + k);
}

// post3T[lt][c(128, pad>=96 zero)][r(512)] from Wpost[lt][128 + (c>>5)*512 + r][c&31]
__global__ __launch_bounds__(512) void tsplit_post3(const float* __restrict__ Wpost,
                                                    unsigned short* __restrict__ hi,
                                                    unsigned short* __restrict__ lo)
{
  int b = blockIdx.x; // 12*128
  int lt = b >> 7, c = b & 127;
  int r = threadIdx.x; // 512
  float v = 0.f;
  if (c < 96)
    v = Wpost[((long long)(lt * 1664 + 128 + (c >> 5) * 512 + r)) * 32 + (c & 31)];
  wsplit(v, hi, lo, ((long long)(lt * 128 + c)) * 512 + r);
}

// WxT[l][c(128)][k(128)] from Wpost[(l*4 + c>>5)*1664 + k][c&31]
__global__ void tsplit_wx(const float* __restrict__ Wpost,
                          unsigned short* __restrict__ hi, unsigned short* __restrict__ lo)
{
  int b = blockIdx.x; // 3*128
  int l = b >> 7, c = b & 127, k = threadIdx.x;
  float v = Wpost[((long long)((l * 4 + (c >> 5)) * 1664 + k)) * 32 + (c & 31)];
  wsplit(v, hi, lo, ((long long)(l * 128 + c)) * 128 + k);
}

// WlinT[l][n][k] from Wlin[l][k][n]
__global__ void tsplit_lin(const float* __restrict__ Wlin,
                           unsigned short* __restrict__ hi, unsigned short* __restrict__ lo)
{
  int b = blockIdx.x; // 3*128
  int l = b >> 7, n = b & 127, k = threadIdx.x;
  float v = Wlin[((long long)(l * 128 + k)) * 128 + n];
  wsplit(v, hi, lo, ((long long)(l * 128 + n)) * 128 + k);
}

// W1T[n(64)][k(128)] from W1[k][n]
__global__ void tsplit_w1(const float* __restrict__ W1,
                          unsigned short* __restrict__ hi, unsigned short* __restrict__ lo)
{
  int n = blockIdx.x; // 64
  int k = threadIdx.x; // 128
  wsplit(W1[k * 64 + n], hi, lo, (long long)n * 128 + k);
}

// ---------------------------------------------------------------------------
// Per-tower aggregation: m = ABt[n][c] + ABt[src][128+c] + Ct[e][c]  (all fp32)
// ---------------------------------------------------------------------------
__global__ __launch_bounds__(128) void aggregate_t(
    const float* __restrict__ ABt, // [N][256]
    const float* __restrict__ Ct,  // [E][128]
    const int* __restrict__ row_off, const int* __restrict__ eidx,
    const int* __restrict__ esrc,
    float* __restrict__ aggt,      // [N][512]
    float* __restrict__ s_arr, float* __restrict__ invs_arr)
{
  int n = blockIdx.x;
  int c = threadIdx.x; // 128
  int beg = row_off[n], end = row_off[n + 1];
  int cnt = end - beg;
  float degc = fmaxf((float)cnt, 1.0f);

  float sum = 0.f, sq = 0.f;
  float mn = INFINITY, mx = -INFINITY;
  float aval = ABt[(long long)n * 256 + c];

  for (int slot = beg; slot < end; ++slot) {
    int e = eidx[slot];
    int sidx = esrc[slot];
    float m = aval + ABt[(long long)sidx * 256 + 128 + c] +
              Ct[(long long)e * 128 + c];
    sum += m;
    sq += m * m;
    mn = fminf(mn, m);
    mx = fmaxf(mx, m);
  }

  if (c == 0) {
    float s = logf(degc + 1.0f) / AVG_LOG_F;
    s_arr[n] = s;
    invs_arr[n] = 1.0f / s;
  }

  float inv = 1.0f / degc;
  float mean = sum * inv;
  float var = sq * inv - mean * mean;
  float stdv = sqrtf(fmaxf(var, 0.f) + 1e-5f);
  float mnv = (cnt > 0) ? mn : 0.f;
  float mxv = (cnt > 0) ? mx : 0.f;
  long long base = (long long)n * 512 + c;
  aggt[base] = mean;
  aggt[base + 128] = mnv;
  aggt[base + 256] = mxv;
  aggt[base + 384] = stdv;
}

// post[n][t*32+o] = Px + P_id + s*P_amp + (1/s)*P_att + bpost
__global__ void combine_post(const float* __restrict__ P,  // [N][384]
                             const float* __restrict__ Px, // [N][128]
                             const float* __restrict__ s_arr,
                             const float* __restrict__ invs_arr,
                             const float* __restrict__ bpost_l, // [128]
                             float* __restrict__ post)          // [N][128]
{
  int n = blockIdx.x, c = threadIdx.x; // 128
  int t = c >> 5, o = c & 31;
  const float* p = P + (long long)n * 384 + t * 96 + o;
  float v = Px[(long long)n * 128 + c] + p[0] + s_arr[n] * p[32] +
            invs_arr[n] * p[64] + bpost_l[c];
  post[(long long)n * 128 + c] = v;
}

// ---------------------------------------------------------------------------
// BatchNorm over N rows, 128 cols (training-mode batch stats, biased var)
// ---------------------------------------------------------------------------
__global__ __launch_bounds__(256) void bn_partial(const float* __restrict__ y,
                                                  float* __restrict__ colsum,
                                                  float* __restrict__ colsq)
{
  int c = threadIdx.x & 127;
  int rh = threadIdx.x >> 7;
  int r0 = blockIdx.x * 128;
  float s = 0.f, q = 0.f;
  for (int r = r0 + rh; r < r0 + 128; r += 2) {
    float v = y[(long long)r * 128 + c];
    s += v;
    q += v * v;
  }
  __shared__ float ps[256], pq[256];
  ps[threadIdx.x] = s;
  pq[threadIdx.x] = q;
  __syncthreads();
  if (threadIdx.x < 128) {
    atomicAdd(&colsum[c], ps[c] + ps[c + 128]);
    atomicAdd(&colsq[c], pq[c] + pq[c + 128]);
  }
}

__global__ void bn_apply(const float* __restrict__ y, const float* __restrict__ colsum,
                         const float* __restrict__ colsq, const float* __restrict__ g,
                         const float* __restrict__ b, float* __restrict__ hout)
{
  int n = blockIdx.x, c = threadIdx.x;
  float mean = colsum[c] * (1.f / 16384.f);
  float var = colsq[c] * (1.f / 16384.f) - mean * mean;
  float v = (y[(long long)n * 128 + c] - mean) * rsqrtf(var + 1e-5f) * g[c] + b[c];
  hout[(long long)n * 128 + c] = fmaxf(v, 0.f);
}

// ---------------------------------------------------------------------------
// Global mean pool + head
// ---------------------------------------------------------------------------
__global__ void pool_add(const float* __restrict__ h, const int* __restrict__ batch,
                         float* __restrict__ pooled, float* __restrict__ cntf)
{
  int n = blockIdx.x, c = threadIdx.x;
  int b = batch[n];
  atomicAdd(&pooled[(long long)b * 128 + c], h[(long long)n * 128 + c]);
  if (c == 0) atomicAdd(&cntf[b], 1.f);
}

__global__ void pool_div(float* __restrict__ pooled, const float* __restrict__ cntf)
{
  int g = blockIdx.x, c = threadIdx.x;
  pooled[(long long)g * 128 + c] /= fmaxf(cntf[g], 1.f);
}

__global__ __launch_bounds__(256) void zstats(const float* __restrict__ z,
                                              float* __restrict__ zm, float* __restrict__ zv)
{
  int j = blockIdx.x; // 64 cols
  float s = 0.f, q = 0.f;
  for (int g = threadIdx.x; g < GG; g += 256) {
    float v = z[g * 64 + j];
    s += v;
    q += v * v;
  }
  __shared__ float ps[256], pq[256];
  ps[threadIdx.x] = s;
  pq[threadIdx.x] = q;
  __syncthreads();
  for (int st = 128; st > 0; st >>= 1) {
    if (threadIdx.x < st) {
      ps[threadIdx.x] += ps[threadIdx.x + st];
      pq[threadIdx.x] += pq[threadIdx.x + st];
    }
    __syncthreads();
  }
  if (threadIdx.x == 0) {
    float m = ps[0] / (float)GG;
    zm[j] = m;
    zv[j] = pq[0] / (float)GG - m * m;
  }
}

__global__ void final_out(const float* __restrict__ z, const float* __restrict__ zm,
                          const float* __restrict__ zv, const float* __restrict__ hg,
                          const float* __restrict__ hb, const float* __restrict__ W2,
                          const float* __restrict__ b2, float* __restrict__ out)
{
  int g = blockIdx.x;
  int j = threadIdx.x; // 64 = one wave
  float v = (z[g * 64 + j] - zm[j]) * rsqrtf(zv[j] + 1e-5f) * hg[j] + hb[j];
  float t = v * W2[j];
#pragma unroll
  for (int off = 32; off > 0; off >>= 1) t += __shfl_down(t, off);
  if (j == 0) out[g] = t + b2[0];
}

// ---------------------------------------------------------------------------
extern "C" void kernel_launch(void* const* d_in, const int* in_sizes, int n_in,
                              void* d_out, int out_size, void* d_ws, size_t ws_size,
                              hipStream_t stream)
{
  (void)in_sizes; (void)n_in; (void)out_size;
  const float* x = (const float*)d_in[0];
  const float* eat = (const float*)d_in[1];
  const int* ei = (const int*)d_in[2];
  const int* batch = (const int*)d_in[3];
  const float* Wa = (const float*)d_in[4];
  const float* ba = (const float*)d_in[5];
  const float* We = (const float*)d_in[6];
  const float* be = (const float*)d_in[7];
  const float* We_conv = (const float*)d_in[8];
  const float* be_conv = (const float*)d_in[9];
  const float* Wpre = (const float*)d_in[10];
  const float* bpre = (const float*)d_in[11];
  const float* Wpost = (const float*)d_in[12];
  const float* bpost = (const float*)d_in[13];
  const float* Wlin = (const float*)d_in[14];
  const float* blin = (const float*)d_in[15];
  const float* bng = (const float*)d_in[16];
  const float* bnb = (const float*)d_in[17];
  const float* W1 = (const float*)d_in[18];
  const float* b1 = (const float*)d_in[19];
  const float* hg = (const float*)d_in[20];
  const float* hb = (const float*)d_in[21];
  const float* W2 = (const float*)d_in[22];
  const float* b2 = (const float*)d_in[23];
  float* out = (float*)d_out;

  const int* srcI = ei;
  const int* dstI = ei + EE;

  char* ws = (char*)d_ws;
  size_t off = 0;
  auto alloc = [&](size_t bytes) -> char* {
    char* p = ws + off;
    off += (bytes + 255) & ~(size_t)255;
    return p;
  };

  // Activations (fp32; ~168 MB total, under proven ~207 MB ceiling)
  float* h0 = (float*)alloc((size_t)NN * 128 * 4);
  float* h1 = (float*)alloc((size_t)NN * 128 * 4);
  float* ea = (float*)alloc((size_t)EE * 128 * 4);
  float* ABt = (float*)alloc((size_t)NN * 256 * 4);
  char* Cregion = alloc((size_t)EE * 128 * 4); // per-tower Ct; later Px|post
  float* Ct = (float*)Cregion;
  float* Px = (float*)Cregion;
  float* post = (float*)(Cregion + (size_t)NN * 128 * 4);
  float* aggt = (float*)alloc((size_t)NN * 512 * 4);
  float* P = (float*)alloc((size_t)NN * 384 * 4);
  float* s_arr = (float*)alloc((size_t)NN * 4);
  float* invs = (float*)alloc((size_t)NN * 4);
  int* degi = (int*)alloc((size_t)NN * 4);
  int* cursor = (int*)alloc((size_t)NN * 4);
  int* row_off = (int*)alloc((size_t)(NN + 1) * 4);
  int* eidx = (int*)alloc((size_t)EE * 4);
  int* esrc = (int*)alloc((size_t)EE * 4);
  // Weights: fp32 folds + packed transposed split-bf16
  float* WfoldF = (float*)alloc((size_t)3 * 128 * 512 * 4);
  float* bfold = (float*)alloc((size_t)3 * 512 * 4);
  unsigned short* preABT_h = (unsigned short*)alloc((size_t)12 * 256 * 128 * 2);
  unsigned short* preABT_l = (unsigned short*)alloc((size_t)12 * 256 * 128 * 2);
  unsigned short* foldT_h = (unsigned short*)alloc((size_t)12 * 128 * 128 * 2);
  unsigned short* foldT_l = (unsigned short*)alloc((size_t)12 * 128 * 128 * 2);
  unsigned short* post3T_h = (unsigned short*)alloc((size_t)12 * 128 * 512 * 2);
  unsigned short* post3T_l = (unsigned short*)alloc((size_t)12 * 128 * 512 * 2);
  unsigned short* wxT_h = (unsigned short*)alloc((size_t)3 * 128 * 128 * 2);
  unsigned short* wxT_l = (unsigned short*)alloc((size_t)3 * 128 * 128 * 2);
  unsigned short* linT_h = (unsigned short*)alloc((size_t)3 * 128 * 128 * 2);
  unsigned short* linT_l = (unsigned short*)alloc((size_t)3 * 128 * 128 * 2);
  unsigned short* w1T_h = (unsigned short*)alloc((size_t)64 * 128 * 2);
  unsigned short* w1T_l = (unsigned short*)alloc((size_t)64 * 128 * 2);
  float* colstats = (float*)alloc(256 * 4);
  float* pooled = (float*)alloc((size_t)GG * 128 * 4);
  float* cntf = (float*)alloc((size_t)GG * 4);
  float* z = (float*)alloc((size_t)GG * 64 * 4);
  float* zm = (float*)alloc(64 * 4);
  float* zv = (float*)alloc(64 * 4);

  if (off > ws_size) return; // workspace too small — bail rather than corrupt

  // ---- graph structure ----
  hipMemsetAsync(degi, 0, (size_t)NN * 4, stream);
  hipMemsetAsync(cursor, 0, (size_t)NN * 4, stream);
  count_deg<<<EE / 256, 256, 0, stream>>>(dstI, degi);
  scan_k<<<1, 1024, 0, stream>>>(degi, row_off);
  scatter_k<<<EE / 256, 256, 0, stream>>>(srcI, dstI, row_off, cursor, eidx, esrc);

  // ---- encoders + weight folds/packing ----
  node_enc<<<NN, 128, 0, stream>>>(x, Wa, ba, h0);
  edge_enc<<<EE, 128, 0, stream>>>(eat, We, be, ea);
  fold_w<<<384, 512, 0, stream>>>(We_conv, Wpre, WfoldF);
  fold_b<<<3, 512, 0, stream>>>(be_conv, Wpre, bpre, bfold);
  tsplit_preAB<<<12 * 256, 128, 0, stream>>>(Wpre, preABT_h, preABT_l);
  tsplit_fold<<<12 * 128, 128, 0, stream>>>(WfoldF, foldT_h, foldT_l);
  tsplit_post3<<<12 * 128, 512, 0, stream>>>(Wpost, post3T_h, post3T_l);
  tsplit_wx<<<3 * 128, 128, 0, stream>>>(Wpost, wxT_h, wxT_l);
  tsplit_lin<<<3 * 128, 128, 0, stream>>>(Wlin, linT_h, linT_l);
  tsplit_w1<<<64, 128, 0, stream>>>(W1, w1T_h, w1T_l);

  float* hc = h0;
  float* hn = h1;
  for (int l = 0; l < 3; ++l) {
    for (int t = 0; t < 4; ++t) {
      int lt = l * 4 + t;
      // ABt: [N,128] @ [128,256]
      mgemm<false, false><<<dim3(NN / 128, 4), 256, 0, stream>>>(
          hc, preABT_h + (size_t)lt * 256 * 128, preABT_l + (size_t)lt * 256 * 128,
          nullptr, ABt, 256, 128, 128, 256);
      // Ct: [E,128] @ [128,128] + bfold_t
      mgemm<true, false><<<dim3(EE / 128, 2), 256, 0, stream>>>(
          ea, foldT_h + (size_t)lt * 128 * 128, foldT_l + (size_t)lt * 128 * 128,
          bfold + l * 512 + t * 128, Ct, 128, 128, 128, 128);
      aggregate_t<<<NN, 128, 0, stream>>>(ABt, Ct, row_off, eidx, esrc, aggt, s_arr, invs);
      // P slice: [N,512] @ [512,96] -> P[:, t*96 .. t*96+96)
      mgemm<false, false><<<dim3(NN / 128, 2), 256, 0, stream>>>(
          aggt, post3T_h + (size_t)lt * 128 * 512, post3T_l + (size_t)lt * 128 * 512,
          nullptr, P + t * 96, 96, 512, 512, 384);
    }
    // Px: [N,128] @ [128,128]
    mgemm<false, false><<<dim3(NN / 128, 2), 256, 0, stream>>>(
        hc, wxT_h + (size_t)l * 128 * 128, wxT_l + (size_t)l * 128 * 128,
        nullptr, Px, 128, 128, 128, 128);
    combine_post<<<NN, 128, 0, stream>>>(P, Px, s_arr, invs, bpost + l * 128, post);
    // lin: [N,128] @ [128,128] + blin
    mgemm<true, false><<<dim3(NN / 128, 2), 256, 0, stream>>>(
        post, linT_h + (size_t)l * 128 * 128, linT_l + (size_t)l * 128 * 128,
        blin + l * 128, hn, 128, 128, 128, 128);
    hipMemsetAsync(colstats, 0, 256 * 4, stream);
    bn_partial<<<128, 256, 0, stream>>>(hn, colstats, colstats + 128);
    bn_apply<<<NN, 128, 0, stream>>>(hn, colstats, colstats + 128,
                                     bng + l * 128, bnb + l * 128, hn);
    float* tmp = hc; hc = hn; hn = tmp;
  }

  // ---- pooling + head ----
  hipMemsetAsync(pooled, 0, (size_t)GG * 128 * 4, stream);
  hipMemsetAsync(cntf, 0, (size_t)GG * 4, stream);
  pool_add<<<NN, 128, 0, stream>>>(hc, batch, pooled, cntf);
  pool_div<<<GG, 128, 0, stream>>>(pooled, cntf);
  mgemm<true, true><<<dim3(GG / 128, 1), 256, 0, stream>>>(
      pooled, w1T_h, w1T_l, b1, z, 64, 128, 128, 64);
  zstats<<<64, 256, 0, stream>>>(z, zm, zv);
  final_out<<<GG, 64, 0, stream>>>(z, zm, zv, hg, hb, W2, b2, out);
}

// Round 5
// 942.639 us; speedup vs baseline: 2.1447x; 1.2496x over previous
//
#include <hip/hip_runtime.h>
#include <hip/hip_bf16.h>

#define DEVFN static __device__ __forceinline__

constexpr int NN = 16384;
constexpr int EE = 65536;
constexpr int GG = 512;
constexpr float AVG_LOG_F = 1.0227308671603782f; // (sum d*log d, d=1..4, hist 1,2,3,4)/10

typedef __attribute__((ext_vector_type(8))) short bfrag; // 8 bf16 = 4 VGPR
typedef __attribute__((ext_vector_type(4))) float f4;    // MFMA C/D

// fp32 -> bf16 (RNE) bit helpers
DEVFN unsigned short f2bf(float f) {
  unsigned int u = __float_as_uint(f);
  unsigned int r = (u + 0x7fffu + ((u >> 16) & 1u)) >> 16;
  return (unsigned short)r;
}
DEVFN float bf2f(unsigned short s) { return __uint_as_float(((unsigned int)s) << 16); }

// ---------------------------------------------------------------------------
// Split-bf16 MFMA GEMM: C[M,Nc] = A[M,K] @ W[K,Nc](fp32, pre-split hi/lo)
// AMODE 0: A fp32, split on the fly (3 MFMA: Ah*Bh + Al*Bh + Ah*Bl ~ fp32)
// AMODE 1: A bf16 (ushort), staged directly (2 MFMA: Ah*Bh + Ah*Bl)
// GATHER: A row r comes from ridx[r] (CSR reorder).
// blockIdx.z batches via element strides bsA/bsW/bsC/bsBias.
// Block 256 = 4 waves; tile M=128, N=64, BK=32. M%128==0, K%32==0, col<Nc guarded.
// ---------------------------------------------------------------------------
template <int AMODE, bool BIAS, bool RELU, bool GATHER>
__global__ __launch_bounds__(256) void mgemm(
    const void* __restrict__ Av, const unsigned short* __restrict__ WThi,
    const unsigned short* __restrict__ WTlo, const float* __restrict__ bias,
    float* __restrict__ C, const int* __restrict__ ridx,
    int Nc, int K, int lda, int ldc,
    long long bsA, long long bsW, long long bsC, int bsBias)
{
  const int z = blockIdx.z;
  WThi += (long long)z * bsW;
  WTlo += (long long)z * bsW;
  C += (long long)z * bsC;
  if (BIAS) bias += (long long)z * bsBias;

  __shared__ __align__(16) unsigned short Ah[128][40];
  __shared__ __align__(16) unsigned short Al[(AMODE == 0) ? 128 : 1][40];
  __shared__ __align__(16) unsigned short Bh[64][40];
  __shared__ __align__(16) unsigned short Bl[64][40];

  const int tid = threadIdx.x;
  const long long bm = (long long)blockIdx.x * 128;
  const int bn = blockIdx.y * 64;
  const int w = tid >> 6;
  const int lane = tid & 63;
  const int quad = lane >> 4;
  const int c16 = lane & 15;

  const int arow = tid >> 1;      // 0..127
  const int sel = tid & 1;        // half of 32-wide k-chunk
  const int brow = tid >> 2;      // 0..63
  const int bk8 = (tid & 3) * 8;  // 0,8,16,24

  long long rowsrc = GATHER ? (long long)ridx[bm + arow] : (bm + arow);

  f4 acc[2][4];
#pragma unroll
  for (int mt = 0; mt < 2; ++mt)
#pragma unroll
    for (int nt = 0; nt < 4; ++nt) acc[mt][nt] = (f4){0.f, 0.f, 0.f, 0.f};

  const unsigned short* whp = WThi + (long long)(bn + brow) * K + bk8;
  const unsigned short* wlp = WTlo + (long long)(bn + brow) * K + bk8;

  for (int k0 = 0; k0 < K; k0 += 32) {
    if (AMODE == 0) {
      const float* A = (const float*)Av + (long long)z * bsA;
      const float* ap = A + rowsrc * lda + k0 + sel * 16;
      float4 v0 = *(const float4*)(ap);
      float4 v1 = *(const float4*)(ap + 4);
      float4 v2 = *(const float4*)(ap + 8);
      float4 v3 = *(const float4*)(ap + 12);
      float va[16] = {v0.x, v0.y, v0.z, v0.w, v1.x, v1.y, v1.z, v1.w,
                      v2.x, v2.y, v2.z, v2.w, v3.x, v3.y, v3.z, v3.w};
#pragma unroll
      for (int i = 0; i < 16; ++i) {
        unsigned short h = f2bf(va[i]);
        Ah[arow][sel * 16 + i] = h;
        Al[arow][sel * 16 + i] = f2bf(va[i] - bf2f(h));
      }
    } else {
      const unsigned short* A = (const unsigned short*)Av + (long long)z * bsA;
      const unsigned short* ap = A + rowsrc * lda + k0 + sel * 16;
      *(uint4*)&Ah[arow][sel * 16] = *(const uint4*)(ap);
      *(uint4*)&Ah[arow][sel * 16 + 8] = *(const uint4*)(ap + 8);
    }
    *(uint4*)&Bh[brow][bk8] = *(const uint4*)(whp + k0);
    *(uint4*)&Bl[brow][bk8] = *(const uint4*)(wlp + k0);
    __syncthreads();

    bfrag ah[2], al[2];
#pragma unroll
    for (int mt = 0; mt < 2; ++mt) {
      int r = w * 32 + mt * 16 + c16;
      ah[mt] = *(const bfrag*)&Ah[r][quad * 8];
      if (AMODE == 0) al[mt] = *(const bfrag*)&Al[r][quad * 8];
    }
#pragma unroll
    for (int nt = 0; nt < 4; ++nt) {
      int r = nt * 16 + c16;
      bfrag bh = *(const bfrag*)&Bh[r][quad * 8];
      bfrag bl = *(const bfrag*)&Bl[r][quad * 8];
#pragma unroll
      for (int mt = 0; mt < 2; ++mt) {
        acc[mt][nt] = __builtin_amdgcn_mfma_f32_16x16x32_bf16(ah[mt], bh, acc[mt][nt], 0, 0, 0);
        if (AMODE == 0)
          acc[mt][nt] = __builtin_amdgcn_mfma_f32_16x16x32_bf16(al[mt], bh, acc[mt][nt], 0, 0, 0);
        acc[mt][nt] = __builtin_amdgcn_mfma_f32_16x16x32_bf16(ah[mt], bl, acc[mt][nt], 0, 0, 0);
      }
    }
    __syncthreads();
  }

  // epilogue: C/D layout col=lane&15, row=quad*4+reg
#pragma unroll
  for (int nt = 0; nt < 4; ++nt) {
    int col = bn + nt * 16 + c16;
    if (col >= Nc) continue;
    float bv = BIAS ? bias[col] : 0.f;
#pragma unroll
    for (int mt = 0; mt < 2; ++mt) {
#pragma unroll
      for (int r = 0; r < 4; ++r) {
        long long row = bm + w * 32 + mt * 16 + quad * 4 + r;
        float v = acc[mt][nt][r] + bv;
        if (RELU) v = fmaxf(v, 0.f);
        C[row * ldc + col] = v;
      }
    }
  }
}

// ---------------------------------------------------------------------------
// Encoders
// ---------------------------------------------------------------------------
__global__ void node_enc(const float* __restrict__ x, const float* __restrict__ Wa,
                         const float* __restrict__ ba, float* __restrict__ h)
{
  int n = blockIdx.x, c = threadIdx.x; // 128
  float acc = ba[c];
#pragma unroll
  for (int k = 0; k < 11; ++k) acc += x[n * 11 + k] * Wa[k * 128 + c];
  h[(long long)n * 128 + c] = fmaxf(acc, 0.f);
}

__global__ void edge_enc(const float* __restrict__ eat, const float* __restrict__ We,
                         const float* __restrict__ be, float* __restrict__ ea)
{
  int e = blockIdx.x, c = threadIdx.x; // 128
  float acc = be[c];
#pragma unroll
  for (int k = 0; k < 4; ++k) acc += eat[e * 4 + k] * We[k * 128 + c];
  ea[(long long)e * 128 + c] = fmaxf(acc, 0.f);
}

// ---------------------------------------------------------------------------
// CSR build: count -> scan -> scatter; s/invs precompute
// ---------------------------------------------------------------------------
__global__ void count_deg(const int* __restrict__ dst, int* __restrict__ degi)
{
  int e = blockIdx.x * 256 + threadIdx.x;
  if (e < EE) atomicAdd(&degi[dst[e]], 1);
}

__global__ __launch_bounds__(1024) void scan_k(const int* __restrict__ degi, int* __restrict__ row_off)
{
  __shared__ int tsum[1024];
  int t = threadIdx.x;
  int local[16];
  int base = t * 16;
  int s = 0;
#pragma unroll
  for (int i = 0; i < 16; ++i) { local[i] = s; s += degi[base + i]; }
  tsum[t] = s;
  __syncthreads();
  for (int off = 1; off < 1024; off <<= 1) {
    int v = (t >= off) ? tsum[t - off] : 0;
    __syncthreads();
    tsum[t] += v;
    __syncthreads();
  }
  int prev = (t == 0) ? 0 : tsum[t - 1];
#pragma unroll
  for (int i = 0; i < 16; ++i) row_off[base + i] = prev + local[i];
  if (t == 1023) row_off[NN] = tsum[1023];
}

__global__ void scatter_k(const int* __restrict__ src, const int* __restrict__ dst,
                          const int* __restrict__ row_off, int* __restrict__ cursor,
                          int* __restrict__ eidx, int* __restrict__ esrc)
{
  int e = blockIdx.x * 256 + threadIdx.x;
  if (e >= EE) return;
  int d = dst[e];
  int pos = atomicAdd(&cursor[d], 1);
  int slot = row_off[d] + pos;
  eidx[slot] = e;
  esrc[slot] = src[e];
}

__global__ void s_init(const int* __restrict__ row_off, float* __restrict__ s_arr,
                       float* __restrict__ invs)
{
  int n = blockIdx.x * 256 + threadIdx.x;
  if (n >= NN) return;
  int cnt = row_off[n + 1] - row_off[n];
  float degc = fmaxf((float)cnt, 1.f);
  float s = logf(degc + 1.f) / AVG_LOG_F;
  s_arr[n] = s;
  invs[n] = 1.f / s;
}

// ---------------------------------------------------------------------------
// Weight folds (fp32) + transpose-split packers (fp32 -> bf16 hi/lo, [N][K])
// ---------------------------------------------------------------------------
__global__ __launch_bounds__(512) void fold_w(const float* __restrict__ We_conv,
                                              const float* __restrict__ Wpre,
                                              float* __restrict__ Wfold)
{
  int k = blockIdx.x & 127, l = blockIdx.x >> 7;
  int t = threadIdx.x >> 7, f = threadIdx.x & 127;
  const float* wc = We_conv + (long long)(l * 128 + k) * 128;
  const float* wp = Wpre + ((long long)((l * 4 + t) * 384 + 256)) * 128 + f;
  float acc = 0.f;
  for (int j = 0; j < 128; ++j) acc += wc[j] * wp[(long long)j * 128];
  Wfold[((long long)(l * 128 + k)) * 512 + threadIdx.x] = acc;
}

__global__ __launch_bounds__(512) void fold_b(const float* __restrict__ be_conv,
                                              const float* __restrict__ Wpre,
                                              const float* __restrict__ bpre,
                                              float* __restrict__ bfold)
{
  int l = blockIdx.x;
  int t = threadIdx.x >> 7, f = threadIdx.x & 127;
  const float* bc = be_conv + l * 128;
  const float* wp = Wpre + ((long long)((l * 4 + t) * 384 + 256)) * 128 + f;
  float acc = bpre[(l * 4 + t) * 128 + f];
  for (int j = 0; j < 128; ++j) acc += bc[j] * wp[(long long)j * 128];
  bfold[l * 512 + threadIdx.x] = acc;
}

DEVFN void wsplit(float v, unsigned short* hi, unsigned short* lo, long long o)
{
  unsigned short h = f2bf(v);
  hi[o] = h;
  lo[o] = f2bf(v - bf2f(h));
}

// preABT[lt][n(256)][k(128)]: n<128 -> A part (Wpre row k); n>=128 -> B part (row 128+k)
__global__ void tsplit_preAB(const float* __restrict__ Wpre,
                             unsigned short* __restrict__ hi, unsigned short* __restrict__ lo)
{
  int b = blockIdx.x; // 12*256
  int lt = b >> 8, n = b & 255, k = threadIdx.x; // 128
  int row = (n < 128) ? k : (128 + k);
  int f = n & 127;
  float v = Wpre[((long long)(lt * 384 + row)) * 128 + f];
  wsplit(v, hi, lo, ((long long)(lt * 256 + n)) * 128 + k);
}

// WfoldT[lt][n(128)][k(128)] from Wfold[l][k][t*128+n]
__global__ void tsplit_fold(const float* __restrict__ Wfold,
                            unsigned short* __restrict__ hi, unsigned short* __restrict__ lo)
{
  int b = blockIdx.x; // 12*128
  int lt = b >> 7, n = b & 127, k = threadIdx.x; // 128
  int l = lt >> 2, t = lt & 3;
  float v = Wfold[((long long)(l * 128 + k)) * 512 + t * 128 + n];
  wsplit(v, hi, lo, ((long long)(lt * 128 + n)) * 128 + k);
}

// post3T[lt][c(128, pad>=96 zero)][r(512)] from Wpost[lt][128 + (c>>5)*512 + r][c&31]
__global__ __launch_bounds__(512) void tsplit_post3(const float* __restrict__ Wpost,
                                                    unsigned short* __restrict__ hi,
                                                    unsigned short* __restrict__ lo)
{
  int b = blockIdx.x; // 12*128
  int lt = b >> 7, c = b & 127;
  int r = threadIdx.x; // 512
  float v = 0.f;
  if (c < 96)
    v = Wpost[((long long)(lt * 1664 + 128 + (c >> 5) * 512 + r)) * 32 + (c & 31)];
  wsplit(v, hi, lo, ((long long)(lt * 128 + c)) * 512 + r);
}

// WxT[l][c(128)][k(128)] from Wpost[(l*4 + c>>5)*1664 + k][c&31]
__global__ void tsplit_wx(const float* __restrict__ Wpost,
                          unsigned short* __restrict__ hi, unsigned short* __restrict__ lo)
{
  int b = blockIdx.x; // 3*128
  int l = b >> 7, c = b & 127, k = threadIdx.x;
  float v = Wpost[((long long)((l * 4 + (c >> 5)) * 1664 + k)) * 32 + (c & 31)];
  wsplit(v, hi, lo, ((long long)(l * 128 + c)) * 128 + k);
}

// WlinT[l][n][k] from Wlin[l][k][n]
__global__ void tsplit_lin(const float* __restrict__ Wlin,
                           unsigned short* __restrict__ hi, unsigned short* __restrict__ lo)
{
  int b = blockIdx.x; // 3*128
  int l = b >> 7, n = b & 127, k = threadIdx.x;
  float v = Wlin[((long long)(l * 128 + k)) * 128 + n];
  wsplit(v, hi, lo, ((long long)(l * 128 + n)) * 128 + k);
}

// W1T[n(64)][k(128)] from W1[k][n]
__global__ void tsplit_w1(const float* __restrict__ W1,
                          unsigned short* __restrict__ hi, unsigned short* __restrict__ lo)
{
  int n = blockIdx.x; // 64
  int k = threadIdx.x; // 128
  wsplit(W1[k * 64 + n], hi, lo, (long long)n * 128 + k);
}

// ---------------------------------------------------------------------------
// Per-tower aggregation. ABs: [N][256] fp32 slab (A|B). Ct: [E][128] fp32 in
// CSR slot order (sequential!). Output aggs: [N][512] bf16 (mean|min|max|std).
// ---------------------------------------------------------------------------
__global__ __launch_bounds__(128) void aggregate_t(
    const float* __restrict__ ABs, const float* __restrict__ Ct,
    const int* __restrict__ row_off, const int* __restrict__ esrc,
    unsigned short* __restrict__ aggs)
{
  int n = blockIdx.x;
  int c = threadIdx.x; // 128
  int beg = row_off[n], end = row_off[n + 1];
  int cnt = end - beg;
  float degc = fmaxf((float)cnt, 1.0f);

  float sum = 0.f, sq = 0.f;
  float mn = INFINITY, mx = -INFINITY;
  float aval = ABs[(long long)n * 256 + c];

  for (int slot = beg; slot < end; ++slot) {
    int sidx = esrc[slot];
    float m = aval + ABs[(long long)sidx * 256 + 128 + c] +
              Ct[(long long)slot * 128 + c];
    sum += m;
    sq += m * m;
    mn = fminf(mn, m);
    mx = fmaxf(mx, m);
  }

  float inv = 1.0f / degc;
  float mean = sum * inv;
  float var = sq * inv - mean * mean;
  float stdv = sqrtf(fmaxf(var, 0.f) + 1e-5f);
  float mnv = (cnt > 0) ? mn : 0.f;
  float mxv = (cnt > 0) ? mx : 0.f;
  long long base = (long long)n * 512 + c;
  aggs[base] = f2bf(mean);
  aggs[base + 128] = f2bf(mnv);
  aggs[base + 256] = f2bf(mxv);
  aggs[base + 384] = f2bf(stdv);
}

// post[n][t*32+o] = Px + P_id + s*P_amp + (1/s)*P_att + bpost
__global__ void combine_post(const float* __restrict__ P,  // [N][384]
                             const float* __restrict__ Px, // [N][128]
                             const float* __restrict__ s_arr,
                             const float* __restrict__ invs_arr,
                             const float* __restrict__ bpost_l, // [128]
                             float* __restrict__ post)          // [N][128]
{
  int n = blockIdx.x, c = threadIdx.x; // 128
  int t = c >> 5, o = c & 31;
  const float* p = P + (long long)n * 384 + t * 96 + o;
  float v = Px[(long long)n * 128 + c] + p[0] + s_arr[n] * p[32] +
            invs_arr[n] * p[64] + bpost_l[c];
  post[(long long)n * 128 + c] = v;
}

// ---------------------------------------------------------------------------
// BatchNorm over N rows, 128 cols (training-mode batch stats, biased var)
// ---------------------------------------------------------------------------
__global__ __launch_bounds__(256) void bn_partial(const float* __restrict__ y,
                                                  float* __restrict__ colsum,
                                                  float* __restrict__ colsq)
{
  int c = threadIdx.x & 127;
  int rh = threadIdx.x >> 7;
  int r0 = blockIdx.x * 128;
  float s = 0.f, q = 0.f;
  for (int r = r0 + rh; r < r0 + 128; r += 2) {
    float v = y[(long long)r * 128 + c];
    s += v;
    q += v * v;
  }
  __shared__ float ps[256], pq[256];
  ps[threadIdx.x] = s;
  pq[threadIdx.x] = q;
  __syncthreads();
  if (threadIdx.x < 128) {
    atomicAdd(&colsum[c], ps[c] + ps[c + 128]);
    atomicAdd(&colsq[c], pq[c] + pq[c + 128]);
  }
}

__global__ void bn_apply(const float* __restrict__ y, const float* __restrict__ colsum,
                         const float* __restrict__ colsq, const float* __restrict__ g,
                         const float* __restrict__ b, float* __restrict__ hout)
{
  int n = blockIdx.x, c = threadIdx.x;
  float mean = colsum[c] * (1.f / 16384.f);
  float var = colsq[c] * (1.f / 16384.f) - mean * mean;
  float v = (y[(long long)n * 128 + c] - mean) * rsqrtf(var + 1e-5f) * g[c] + b[c];
  hout[(long long)n * 128 + c] = fmaxf(v, 0.f);
}

// ---------------------------------------------------------------------------
// Global mean pool + head
// ---------------------------------------------------------------------------
__global__ void pool_add(const float* __restrict__ h, const int* __restrict__ batch,
                         float* __restrict__ pooled, float* __restrict__ cntf)
{
  int n = blockIdx.x, c = threadIdx.x;
  int b = batch[n];
  atomicAdd(&pooled[(long long)b * 128 + c], h[(long long)n * 128 + c]);
  if (c == 0) atomicAdd(&cntf[b], 1.f);
}

__global__ void pool_div(float* __restrict__ pooled, const float* __restrict__ cntf)
{
  int g = blockIdx.x, c = threadIdx.x;
  pooled[(long long)g * 128 + c] /= fmaxf(cntf[g], 1.f);
}

__global__ __launch_bounds__(256) void zstats(const float* __restrict__ z,
                                              float* __restrict__ zm, float* __restrict__ zv)
{
  int j = blockIdx.x; // 64 cols
  float s = 0.f, q = 0.f;
  for (int g = threadIdx.x; g < GG; g += 256) {
    float v = z[g * 64 + j];
    s += v;
    q += v * v;
  }
  __shared__ float ps[256], pq[256];
  ps[threadIdx.x] = s;
  pq[threadIdx.x] = q;
  __syncthreads();
  for (int st = 128; st > 0; st >>= 1) {
    if (threadIdx.x < st) {
      ps[threadIdx.x] += ps[threadIdx.x + st];
      pq[threadIdx.x] += pq[threadIdx.x + st];
    }
    __syncthreads();
  }
  if (threadIdx.x == 0) {
    float m = ps[0] / (float)GG;
    zm[j] = m;
    zv[j] = pq[0] / (float)GG - m * m;
  }
}

__global__ void final_out(const float* __restrict__ z, const float* __restrict__ zm,
                          const float* __restrict__ zv, const float* __restrict__ hg,
                          const float* __restrict__ hb, const float* __restrict__ W2,
                          const float* __restrict__ b2, float* __restrict__ out)
{
  int g = blockIdx.x;
  int j = threadIdx.x; // 64 = one wave
  float v = (z[g * 64 + j] - zm[j]) * rsqrtf(zv[j] + 1e-5f) * hg[j] + hb[j];
  float t = v * W2[j];
#pragma unroll
  for (int off = 32; off > 0; off >>= 1) t += __shfl_down(t, off);
  if (j == 0) out[g] = t + b2[0];
}

// ---------------------------------------------------------------------------
extern "C" void kernel_launch(void* const* d_in, const int* in_sizes, int n_in,
                              void* d_out, int out_size, void* d_ws, size_t ws_size,
                              hipStream_t stream)
{
  (void)in_sizes; (void)n_in; (void)out_size;
  const float* x = (const float*)d_in[0];
  const float* eat = (const float*)d_in[1];
  const int* ei = (const int*)d_in[2];
  const int* batch = (const int*)d_in[3];
  const float* Wa = (const float*)d_in[4];
  const float* ba = (const float*)d_in[5];
  const float* We = (const float*)d_in[6];
  const float* be = (const float*)d_in[7];
  const float* We_conv = (const float*)d_in[8];
  const float* be_conv = (const float*)d_in[9];
  const float* Wpre = (const float*)d_in[10];
  const float* bpre = (const float*)d_in[11];
  const float* Wpost = (const float*)d_in[12];
  const float* bpost = (const float*)d_in[13];
  const float* Wlin = (const float*)d_in[14];
  const float* blin = (const float*)d_in[15];
  const float* bng = (const float*)d_in[16];
  const float* bnb = (const float*)d_in[17];
  const float* W1 = (const float*)d_in[18];
  const float* b1 = (const float*)d_in[19];
  const float* hg = (const float*)d_in[20];
  const float* hb = (const float*)d_in[21];
  const float* W2 = (const float*)d_in[22];
  const float* b2 = (const float*)d_in[23];
  float* out = (float*)d_out;

  const int* srcI = ei;
  const int* dstI = ei + EE;

  char* ws = (char*)d_ws;
  size_t off = 0;
  auto alloc = [&](size_t bytes) -> char* {
    char* p = ws + off;
    off += (bytes + 255) & ~(size_t)255;
    return p;
  };

  // ~251 MB total (ws = 256 MiB, measured via harness 0xAA fill)
  float* h0 = (float*)alloc((size_t)NN * 128 * 4);          //  8.4 MB
  float* h1 = (float*)alloc((size_t)NN * 128 * 4);          //  8.4 MB
  float* ea = (float*)alloc((size_t)EE * 128 * 4);          // 33.6 MB
  float* AB = (float*)alloc((size_t)4 * NN * 256 * 4);      // 67.1 MB  [T][N][256]
  char* Cregion = alloc((size_t)EE * 128 * 4);              // 33.6 MB  Ct; later Px|post
  float* Ct = (float*)Cregion;
  float* Px = (float*)Cregion;
  float* post = (float*)(Cregion + (size_t)NN * 128 * 4);
  unsigned short* aggt = (unsigned short*)alloc((size_t)4 * NN * 512 * 2); // 67.1 MB bf16 [T][N][512]
  float* P = (float*)alloc((size_t)NN * 384 * 4);           // 25.2 MB
  float* s_arr = (float*)alloc((size_t)NN * 4);
  float* invs = (float*)alloc((size_t)NN * 4);
  int* degi = (int*)alloc((size_t)NN * 4);
  int* cursor = (int*)alloc((size_t)NN * 4);
  int* row_off = (int*)alloc((size_t)(NN + 1) * 4);
  int* eidx = (int*)alloc((size_t)EE * 4);
  int* esrc = (int*)alloc((size_t)EE * 4);
  float* WfoldF = (float*)alloc((size_t)3 * 128 * 512 * 4);
  float* bfold = (float*)alloc((size_t)3 * 512 * 4);
  unsigned short* preABT_h = (unsigned short*)alloc((size_t)12 * 256 * 128 * 2);
  unsigned short* preABT_l = (unsigned short*)alloc((size_t)12 * 256 * 128 * 2);
  unsigned short* foldT_h = (unsigned short*)alloc((size_t)12 * 128 * 128 * 2);
  unsigned short* foldT_l = (unsigned short*)alloc((size_t)12 * 128 * 128 * 2);
  unsigned short* post3T_h = (unsigned short*)alloc((size_t)12 * 128 * 512 * 2);
  unsigned short* post3T_l = (unsigned short*)alloc((size_t)12 * 128 * 512 * 2);
  unsigned short* wxT_h = (unsigned short*)alloc((size_t)3 * 128 * 128 * 2);
  unsigned short* wxT_l = (unsigned short*)alloc((size_t)3 * 128 * 128 * 2);
  unsigned short* linT_h = (unsigned short*)alloc((size_t)3 * 128 * 128 * 2);
  unsigned short* linT_l = (unsigned short*)alloc((size_t)3 * 128 * 128 * 2);
  unsigned short* w1T_h = (unsigned short*)alloc((size_t)64 * 128 * 2);
  unsigned short* w1T_l = (unsigned short*)alloc((size_t)64 * 128 * 2);
  float* colstats = (float*)alloc(256 * 4);
  float* pooled = (float*)alloc((size_t)GG * 128 * 4);
  float* cntf = (float*)alloc((size_t)GG * 4);
  float* zbuf = (float*)alloc((size_t)GG * 64 * 4);
  float* zm = (float*)alloc(64 * 4);
  float* zv = (float*)alloc(64 * 4);

  if (off > ws_size) return; // bail rather than corrupt

  // ---- graph structure ----
  hipMemsetAsync(degi, 0, (size_t)NN * 4, stream);
  hipMemsetAsync(cursor, 0, (size_t)NN * 4, stream);
  count_deg<<<EE / 256, 256, 0, stream>>>(dstI, degi);
  scan_k<<<1, 1024, 0, stream>>>(degi, row_off);
  scatter_k<<<EE / 256, 256, 0, stream>>>(srcI, dstI, row_off, cursor, eidx, esrc);
  s_init<<<NN / 256, 256, 0, stream>>>(row_off, s_arr, invs);

  // ---- encoders + weight folds/packing ----
  node_enc<<<NN, 128, 0, stream>>>(x, Wa, ba, h0);
  edge_enc<<<EE, 128, 0, stream>>>(eat, We, be, ea);
  fold_w<<<384, 512, 0, stream>>>(We_conv, Wpre, WfoldF);
  fold_b<<<3, 512, 0, stream>>>(be_conv, Wpre, bpre, bfold);
  tsplit_preAB<<<12 * 256, 128, 0, stream>>>(Wpre, preABT_h, preABT_l);
  tsplit_fold<<<12 * 128, 128, 0, stream>>>(WfoldF, foldT_h, foldT_l);
  tsplit_post3<<<12 * 128, 512, 0, stream>>>(Wpost, post3T_h, post3T_l);
  tsplit_wx<<<3 * 128, 128, 0, stream>>>(Wpost, wxT_h, wxT_l);
  tsplit_lin<<<3 * 128, 128, 0, stream>>>(Wlin, linT_h, linT_l);
  tsplit_w1<<<64, 128, 0, stream>>>(W1, w1T_h, w1T_l);

  float* hc = h0;
  float* hn = h1;
  for (int l = 0; l < 3; ++l) {
    // AB all towers: [N,128] @ [128,256] (z=4) -> fp32 [T][N][256]
    mgemm<0, false, false, false><<<dim3(NN / 128, 4, 4), 256, 0, stream>>>(
        hc, preABT_h + (size_t)l * 4 * 256 * 128, preABT_l + (size_t)l * 4 * 256 * 128,
        nullptr, AB, nullptr, 256, 128, 128, 256,
        0, (long long)256 * 128, (long long)NN * 256, 0);
    for (int t = 0; t < 4; ++t) {
      int lt = l * 4 + t;
      // Ct in CSR slot order: row s <- ea[eidx[s]]; [E,128]@[128,128]+bfold_t
      mgemm<0, true, false, true><<<dim3(EE / 128, 2, 1), 256, 0, stream>>>(
          ea, foldT_h + (size_t)lt * 128 * 128, foldT_l + (size_t)lt * 128 * 128,
          bfold + l * 512 + t * 128, Ct, eidx, 128, 128, 128, 128, 0, 0, 0, 0);
      aggregate_t<<<NN, 128, 0, stream>>>(AB + (size_t)t * NN * 256, Ct, row_off, esrc,
                                          aggt + (size_t)t * NN * 512);
    }
    // P all towers: bf16 [N,512] @ [512,96] (z=4) -> P[:, z*96..]
    mgemm<1, false, false, false><<<dim3(NN / 128, 2, 4), 256, 0, stream>>>(
        aggt, post3T_h + (size_t)l * 4 * 128 * 512, post3T_l + (size_t)l * 4 * 128 * 512,
        nullptr, P, nullptr, 96, 512, 512, 384,
        (long long)NN * 512, (long long)128 * 512, 96, 0);
    // Px: [N,128] @ [128,128]
    mgemm<0, false, false, false><<<dim3(NN / 128, 2, 1), 256, 0, stream>>>(
        hc, wxT_h + (size_t)l * 128 * 128, wxT_l + (size_t)l * 128 * 128,
        nullptr, Px, nullptr, 128, 128, 128, 128, 0, 0, 0, 0);
    combine_post<<<NN, 128, 0, stream>>>(P, Px, s_arr, invs, bpost + l * 128, post);
    // lin: [N,128] @ [128,128] + blin
    mgemm<0, true, false, false><<<dim3(NN / 128, 2, 1), 256, 0, stream>>>(
        post, linT_h + (size_t)l * 128 * 128, linT_l + (size_t)l * 128 * 128,
        blin + l * 128, hn, nullptr, 128, 128, 128, 128, 0, 0, 0, 0);
    hipMemsetAsync(colstats, 0, 256 * 4, stream);
    bn_partial<<<128, 256, 0, stream>>>(hn, colstats, colstats + 128);
    bn_apply<<<NN, 128, 0, stream>>>(hn, colstats, colstats + 128,
                                     bng + l * 128, bnb + l * 128, hn);
    float* tmp = hc; hc = hn; hn = tmp;
  }

  // ---- pooling + head ----
  hipMemsetAsync(pooled, 0, (size_t)GG * 128 * 4, stream);
  hipMemsetAsync(cntf, 0, (size_t)GG * 4, stream);
  pool_add<<<NN, 128, 0, stream>>>(hc, batch, pooled, cntf);
  pool_div<<<GG, 128, 0, stream>>>(pooled, cntf);
  mgemm<0, true, true, false><<<dim3(GG / 128, 1, 1), 256, 0, stream>>>(
      pooled, w1T_h, w1T_l, b1, zbuf, nullptr, 64, 128, 128, 64, 0, 0, 0, 0);
  zstats<<<64, 256, 0, stream>>>(zbuf, zm, zv);
  final_out<<<GG, 64, 0, stream>>>(zbuf, zm, zv, hg, hb, W2, b2, out);
}